// Round 6
// baseline (402.098 us; speedup 1.0000x reference)
//
#include <hip/hip_runtime.h>

typedef _Float16 f16;
typedef f16 f16x8 __attribute__((ext_vector_type(8)));
typedef f16 f16x4v __attribute__((ext_vector_type(4)));
typedef float f32x4 __attribute__((ext_vector_type(4)));

// async global->LDS, 16B per lane (QKV kernel only).
__device__ __forceinline__ void async_ld16(const void* g, void* l) {
    __builtin_amdgcn_global_load_lds(
        (const __attribute__((address_space(1))) unsigned int*)g,
        (__attribute__((address_space(3))) unsigned int*)l, 16, 0, 0);
}

// ---------------- fused QKV projection (round-5 structure) ----------------
// C[m,n] = sum_k inp[m,k] * W3[n,k], tile 128x128, K-step 64 (2 x BK32).
// Segment (nBase>>10): 0 -> Q16 (+b_q), 1 -> K16 (+b_k), 2 -> Vt16 [b][e][s].
__global__ __launch_bounds__(256) void qkv_gemm(
    const f16* __restrict__ A, const f16* __restrict__ Bt,
    const float* __restrict__ b_q, const float* __restrict__ b_k,
    const float* __restrict__ b_v,
    f16* __restrict__ C0, f16* __restrict__ C1, f16* __restrict__ C2)
{
    const int bx = blockIdx.x, by = blockIdx.y;

    __shared__ __align__(16) f16 smem[256 * 64];
    f16* sA = smem;                    // halves at h*4096
    f16* sB = smem + 128 * 64;

    const int tid  = threadIdx.x;
    const int wave = tid >> 6, lane = tid & 63;
    const int wrow = wave >> 1, wcol = wave & 1;
    const int quad = lane >> 4, l16 = lane & 15;
    const int mBase = by * 128, nBase = bx * 128;

    f32x4 acc[4][4];
#pragma unroll
    for (int i = 0; i < 4; ++i)
#pragma unroll
        for (int j = 0; j < 4; ++j)
            acc[i][j] = (f32x4){0.f, 0.f, 0.f, 0.f};

    const f16* aP[2];
    const f16* bP[2];
#pragma unroll
    for (int r = 0; r < 2; ++r) {
        aP[r] = A  + (long)(mBase + ((r * 256 + tid) >> 2)) * 1024 + ((tid * 8) & 31);
        bP[r] = Bt + (long)(nBase + ((r * 256 + tid) >> 2)) * 1024 + ((tid * 8) & 31);
    }
    const int ldsOff = wave * 512;

    for (int kt = 0; kt < 16; ++kt) {          // K=1024, step 64
#pragma unroll
        for (int h = 0; h < 2; ++h)
#pragma unroll
            for (int r = 0; r < 2; ++r) {
                async_ld16(aP[r] + h * 32, &sA[h * 4096 + r * 2048 + ldsOff]);
                async_ld16(bP[r] + h * 32, &sB[h * 4096 + r * 2048 + ldsOff]);
            }
#pragma unroll
        for (int r = 0; r < 2; ++r) { aP[r] += 64; bP[r] += 64; }
        __syncthreads();

#pragma unroll
        for (int h = 0; h < 2; ++h) {
            f16x8 af[4], bf[4];
#pragma unroll
            for (int i = 0; i < 4; ++i)
                af[i] = *(const f16x8*)&sA[h * 4096 + (wrow * 64 + i * 16 + l16) * 32 + quad * 8];
#pragma unroll
            for (int j = 0; j < 4; ++j)
                bf[j] = *(const f16x8*)&sB[h * 4096 + (wcol * 64 + j * 16 + l16) * 32 + quad * 8];
#pragma unroll
            for (int i = 0; i < 4; ++i)
#pragma unroll
                for (int j = 0; j < 4; ++j)
                    acc[i][j] = __builtin_amdgcn_mfma_f32_16x16x32_f16(af[i], bf[j], acc[i][j], 0, 0, 0);
        }
        __syncthreads();
    }

    // epilogue. C/D layout: col = lane&15, row = quad*4 + reg  [m89]
    const int seg = nBase >> 10;
    const float* bs = (seg == 0) ? b_q : (seg == 1) ? b_k : b_v;
    const int lcb = (nBase & 1023) + wcol * 64;
    float bvv[4];
#pragma unroll
    for (int j = 0; j < 4; ++j) bvv[j] = bs[lcb + j * 16 + l16];

    if (seg < 2) {
        // 64 consecutive f16 per wave-store: fully line-coalesced.
        f16* dst = (seg == 0) ? C0 : C1;
#pragma unroll
        for (int i = 0; i < 4; ++i)
#pragma unroll
            for (int j = 0; j < 4; ++j)
#pragma unroll
                for (int r = 0; r < 4; ++r) {
                    const int row = mBase + wrow * 64 + i * 16 + quad * 4 + r;
                    dst[(long)row * 1024 + lcb + j * 16 + l16] = (f16)(acc[i][j][r] + bvv[j]);
                }
    } else {
        // V: transpose tile through LDS, store coalesced along s.
        const int b = mBase >> 11, s0 = mBase & 2047;
        f16* epiT = smem;   // 64 x 136 f16
#pragma unroll
        for (int h = 0; h < 2; ++h) {
            if (wcol == h) {
#pragma unroll
                for (int i = 0; i < 4; ++i)
#pragma unroll
                    for (int j = 0; j < 4; ++j) {
                        f16x4v pk;
#pragma unroll
                        for (int r = 0; r < 4; ++r)
                            pk[r] = (f16)(acc[i][j][r] + bvv[j]);
                        *(f16x4v*)&epiT[(j * 16 + l16) * 136 + wrow * 64 + i * 16 + quad * 4] = pk;
                    }
            }
            __syncthreads();
            const int er = tid >> 2;
            f16* dst = C2 + ((long)b * 1024 + (nBase & 1023) + h * 64 + er) * 2048 + s0;
#pragma unroll
            for (int cc = 0; cc < 4; ++cc) {
                const int ch = (tid & 3) + cc * 4;
                *(f16x8*)&dst[ch * 8] = *(const f16x8*)&epiT[er * 136 + ch * 8];
            }
            __syncthreads();
        }
    }
}

// ---------------- barrier-free scores: P = exp(QK^T/32) ----------------
// No LDS, no __syncthreads. Each wave = independent 64q x 64k tile; MFMA
// fragments loaded straight from global (16B/lane, 64B-sector aligned).
// Block = 2 waves (64q x 128k) sharing the af rows via L1.
__global__ __launch_bounds__(128) void scores_kernel(
    const f16* __restrict__ Q16, const f16* __restrict__ K16,
    f16* __restrict__ P, float* __restrict__ rsum,
    const int* __restrict__ maskedp)
{
    const int b = blockIdx.z;
    const int masked = *maskedp;
    const int bx = blockIdx.x, by = blockIdx.y;
    if (masked && bx * 128 > by * 64 + 63) return;   // fully-masked tile
    const int wave = threadIdx.x >> 6, lane = threadIdx.x & 63;
    const int quad = lane >> 4, l16 = lane & 15;
    const int mW = by * 64;                // q rows
    const int nW = bx * 128 + wave * 64;   // k cols
    const f16* Qb = Q16 + (long)b * 2048 * 1024;
    const f16* Kb = K16 + (long)b * 2048 * 1024;

    const f16* aP[4];
    const f16* bP[4];
#pragma unroll
    for (int i = 0; i < 4; ++i)
        aP[i] = Qb + (long)(mW + i * 16 + l16) * 1024 + quad * 8;
#pragma unroll
    for (int j = 0; j < 4; ++j)
        bP[j] = Kb + (long)(nW + j * 16 + l16) * 1024 + quad * 8;

    f32x4 acc[4][4];
#pragma unroll
    for (int i = 0; i < 4; ++i)
#pragma unroll
        for (int j = 0; j < 4; ++j)
            acc[i][j] = (f32x4){0.f, 0.f, 0.f, 0.f};

    for (int k0 = 0; k0 < 1024; k0 += 128) {
#pragma unroll
        for (int u = 0; u < 4; ++u) {     // imm-offset sub-steps
            const int ko = k0 + u * 32;
            f16x8 af[4], bf[4];
#pragma unroll
            for (int i = 0; i < 4; ++i) af[i] = *(const f16x8*)(aP[i] + ko);
#pragma unroll
            for (int j = 0; j < 4; ++j) bf[j] = *(const f16x8*)(bP[j] + ko);
#pragma unroll
            for (int i = 0; i < 4; ++i)
#pragma unroll
                for (int j = 0; j < 4; ++j)
                    acc[i][j] = __builtin_amdgcn_mfma_f32_16x16x32_f16(af[i], bf[j], acc[i][j], 0, 0, 0);
        }
    }

    f16* Pb = P + (long)b * 2048 * 2048;
    float* rsb = rsum + b * 2048;
#pragma unroll
    for (int i = 0; i < 4; ++i) {
        float rs[4] = {0.f, 0.f, 0.f, 0.f};
#pragma unroll
        for (int j = 0; j < 4; ++j)
#pragma unroll
            for (int r = 0; r < 4; ++r) {
                const int row = mW + i * 16 + quad * 4 + r;
                const int col = nW + j * 16 + l16;
                float e = __expf(acc[i][j][r] * 0.03125f);
                if (masked && col > row) e = 0.f;
                const f16 hv = (f16)e;
                Pb[(long)row * 2048 + col] = hv;
                rs[r] += (float)hv;
            }
#pragma unroll
        for (int r = 0; r < 4; ++r) {
            float s = rs[r];
            s += __shfl_xor(s, 1);
            s += __shfl_xor(s, 2);
            s += __shfl_xor(s, 4);
            s += __shfl_xor(s, 8);
            if (l16 == 0)
                atomicAdd(&rsb[mW + i * 16 + quad * 4 + r], s);
        }
    }
}

// ---------------- barrier-free PV: out = (P @ V) / rowsum ----------------
// Same structure; A = P [q][k], B = Vt [e][s]; K-loop causal-limited
// (P is zero-padded to 128-boundaries by the scores epilogue).
__global__ __launch_bounds__(128) void pv_kernel(
    const f16* __restrict__ P, const f16* __restrict__ Vt,
    const float* __restrict__ rsum, float* __restrict__ out,
    const int* __restrict__ maskedp)
{
    const int b = blockIdx.z;
    const int masked = *maskedp;
    const int bx = blockIdx.x;
    const int by = gridDim.y - 1 - blockIdx.y;   // heavy (long-K) first
    const int kmax = masked ? (((by >> 1) + 1) << 7) : 2048;
    const int wave = threadIdx.x >> 6, lane = threadIdx.x & 63;
    const int quad = lane >> 4, l16 = lane & 15;
    const int mW = by * 64;                // q rows
    const int nW = bx * 128 + wave * 64;   // e cols
    const f16* Pb = P  + (long)b * 2048 * 2048;
    const f16* Vb = Vt + (long)b * 1024 * 2048;

    const f16* aP[4];
    const f16* bP[4];
#pragma unroll
    for (int i = 0; i < 4; ++i)
        aP[i] = Pb + (long)(mW + i * 16 + l16) * 2048 + quad * 8;
#pragma unroll
    for (int j = 0; j < 4; ++j)
        bP[j] = Vb + (long)(nW + j * 16 + l16) * 2048 + quad * 8;

    f32x4 acc[4][4];
#pragma unroll
    for (int i = 0; i < 4; ++i)
#pragma unroll
        for (int j = 0; j < 4; ++j)
            acc[i][j] = (f32x4){0.f, 0.f, 0.f, 0.f};

    for (int k0 = 0; k0 < kmax; k0 += 128) {
#pragma unroll
        for (int u = 0; u < 4; ++u) {
            const int ko = k0 + u * 32;
            f16x8 af[4], bf[4];
#pragma unroll
            for (int i = 0; i < 4; ++i) af[i] = *(const f16x8*)(aP[i] + ko);
#pragma unroll
            for (int j = 0; j < 4; ++j) bf[j] = *(const f16x8*)(bP[j] + ko);
#pragma unroll
            for (int i = 0; i < 4; ++i)
#pragma unroll
                for (int j = 0; j < 4; ++j)
                    acc[i][j] = __builtin_amdgcn_mfma_f32_16x16x32_f16(af[i], bf[j], acc[i][j], 0, 0, 0);
        }
    }

    const float* rsb = rsum + b * 2048;
#pragma unroll
    for (int i = 0; i < 4; ++i)
#pragma unroll
        for (int r = 0; r < 4; ++r) {
            const int row = mW + i * 16 + quad * 4 + r;
            const float inv = 1.f / rsb[row];
#pragma unroll
            for (int j = 0; j < 4; ++j)
                out[((long)b * 2048 + row) * 1024 + nW + j * 16 + l16] = acc[i][j][r] * inv;
        }
}

__global__ void cvt_inp(const float* __restrict__ in, f16* __restrict__ out, int n4)
{
    const int i = blockIdx.x * blockDim.x + threadIdx.x;
    if (i >= n4) return;
    const float4 v = ((const float4*)in)[i];
    f16x4v o;
    o[0] = (f16)v.x; o[1] = (f16)v.y; o[2] = (f16)v.z; o[3] = (f16)v.w;
    ((f16x4v*)out)[i] = o;
}

// three 1024x1024 weight matrices -> contiguous f16 [3072][1024]
__global__ void cvt_w3(const float* __restrict__ W0, const float* __restrict__ W1,
                       const float* __restrict__ W2, f16* __restrict__ out)
{
    const int bxx = blockIdx.x;            // 3072 blocks
    const int which = bxx >> 10;
    const float* src = (which == 0) ? W0 : (which == 1) ? W1 : W2;
    const int i = (bxx & 1023) * 256 + threadIdx.x;
    const float4 v = ((const float4*)src)[i];
    f16x4v o;
    o[0] = (f16)v.x; o[1] = (f16)v.y; o[2] = (f16)v.z; o[3] = (f16)v.w;
    ((f16x4v*)(out + (long)which * 1024 * 1024))[i] = o;
}

extern "C" void kernel_launch(void* const* d_in, const int* in_sizes, int n_in,
                              void* d_out, int out_size, void* d_ws, size_t ws_size,
                              hipStream_t stream)
{
    const float* inp = (const float*)d_in[0];
    const int* masked = (const int*)d_in[1];
    const float* Wq = (const float*)d_in[2];
    const float* bq = (const float*)d_in[3];
    const float* Wk = (const float*)d_in[4];
    const float* bk = (const float*)d_in[5];
    const float* Wv = (const float*)d_in[6];
    const float* bv = (const float*)d_in[7];
    float* out = (float*)d_out;

    const int Bb = 4, S = 2048, E = 1024;
    const long nTok = (long)Bb * S;   // 8192

    // workspace (~102 MB). W3 segments must stay contiguous (one Bt operand).
    char* ws = (char*)d_ws;
    f16* inp16 = (f16*)ws;   ws += nTok * E * 2;         // 16 MB
    f16* W3    = (f16*)ws;   ws += (long)3 * E * E * 2;  //  6 MB
    f16* Q16   = (f16*)ws;   ws += nTok * E * 2;         // 16 MB
    f16* K16   = (f16*)ws;   ws += nTok * E * 2;         // 16 MB
    f16* Vt16  = (f16*)ws;   ws += nTok * E * 2;         // 16 MB ([b][e][s])
    f16* P16   = (f16*)ws;   ws += (long)Bb * S * S * 2; // 32 MB
    float* rsum = (float*)ws; ws += nTok * 4;            // 32 KB

    dim3 blk(256);

    hipMemsetAsync(rsum, 0, nTok * 4, stream);
    cvt_inp<<<(int)(nTok * E / 4 / 256), blk, 0, stream>>>(inp, inp16, (int)(nTok * E / 4));
    cvt_w3<<<3 * 1024, blk, 0, stream>>>(Wq, Wk, Wv, W3);

    // fused QKV: A = inp (8192x1024 tokens), Bt = W3 (3072x1024)
    qkv_gemm<<<dim3(24, 64, 1), blk, 0, stream>>>(
        inp16, W3, bq, bk, bv, Q16, K16, Vt16);

    // P = exp(QK^T/32) + rowsum atomics (barrier-free, causal tile skip)
    scores_kernel<<<dim3(S / 128, S / 64, Bb), dim3(128), 0, stream>>>(
        Q16, K16, P16, rsum, masked);

    // out = (P @ V)/rowsum (barrier-free, K causal-limited, heavy-first)
    pv_kernel<<<dim3(E / 128, S / 64, Bb), dim3(128), 0, stream>>>(
        P16, Vt16, rsum, out, masked);
}

// Round 7
// 277.434 us; speedup vs baseline: 1.4493x; 1.4493x over previous
//
#include <hip/hip_runtime.h>

typedef _Float16 f16;
typedef f16 f16x8 __attribute__((ext_vector_type(8)));
typedef f16 f16x4v __attribute__((ext_vector_type(4)));
typedef float f32x4 __attribute__((ext_vector_type(4)));

// async global->LDS, 16B per lane. LDS dest is wave-uniform base; HW scatters
// lane i's 16B to base + i*16. (No padding possible -> keep BK=32 layout.)
// NOTE (r6): direct per-fragment global loads instead of LDS staging regress
// 4x (MfmaUtil 4.5%) -- exposed VMEM latency. Keep LDS staging.
__device__ __forceinline__ void async_ld16(const void* g, void* l) {
    __builtin_amdgcn_global_load_lds(
        (const __attribute__((address_space(1))) unsigned int*)g,
        (__attribute__((address_space(3))) unsigned int*)l, 16, 0, 0);
}

// C[m,n] = sum_k A[m,k] * Bt[n,k], tile 128 x 128, K-step 64 = 2 x BK32
// sub-tiles per barrier pair. All modes use the full 128x128 tile (r6 lesson:
// TBN=64 halves MFMA-per-barrier and cost ~35 us across scores+PV).
// MODE 0: fused QKV projection, N=3072. Segment (nBase>>10):
//       0 -> Q16 row-major (+b_q), 1 -> K16 row-major (+b_k),
//       2 -> Vt16 per-batch transposed [b][e][s] (+b_v) via LDS transpose.
// MODE 2: P[q][k] = exp(score/32) f16, causal-zeroed k>q; per-row partial
//       sums atomicAdd'ed into rowsum (no max-sub: |s/32| < ~4).
// MODE 3: out = (P @ V) / rowsum[q], fp32; K-loop causal-limited.
template <int MODE>
__global__ __launch_bounds__(256) void gemm_bt(
    const f16* __restrict__ A, long strideAb, int lda,
    const f16* __restrict__ Bt, long strideBb, int ldb,
    const float* __restrict__ b_q, const float* __restrict__ b_k,
    const float* __restrict__ b_v, float* __restrict__ rowsum,
    void* __restrict__ C0, void* __restrict__ C1, void* __restrict__ C2,
    long strideCb, int K,
    const int* __restrict__ maskedp)
{
    const int bx = blockIdx.x, bz = blockIdx.z;
    // heavy (long-K / unskipped) rows launch first for causal modes
    const int by = (MODE >= 2) ? (gridDim.y - 1 - blockIdx.y) : blockIdx.y;
    const int masked = maskedp ? *maskedp : 1;
    if (MODE == 2 && masked && bx > by) return;      // fully-masked tile
    int kmax = K;
    if (MODE == 3 && masked) kmax = min(K, (by + 1) * 128);

    A  += (long)bz * strideAb;
    Bt += (long)bz * strideBb;

    // two BK=32 sub-tiles of A (128x32) + two of B (128x32)
    __shared__ __align__(16) f16 smem[256 * 64];
    f16* sA = smem;                    // halves at h*4096
    f16* sB = smem + 128 * 64;

    const int tid  = threadIdx.x;
    const int wave = tid >> 6, lane = tid & 63;
    const int wrow = wave >> 1, wcol = wave & 1;
    const int quad = lane >> 4, l16 = lane & 15;
    const int mBase = by * 128, nBase = bx * 128;

    f32x4 acc[4][4];
#pragma unroll
    for (int i = 0; i < 4; ++i)
#pragma unroll
        for (int j = 0; j < 4; ++j)
            acc[i][j] = (f32x4){0.f, 0.f, 0.f, 0.f};

    // pointer-bumped staging addresses (+64 f16 per outer iter)
    const f16* aP[2];
    const f16* bP[2];
#pragma unroll
    for (int r = 0; r < 2; ++r) {
        aP[r] = A  + (long)(mBase + ((r * 256 + tid) >> 2)) * lda + ((tid * 8) & 31);
        bP[r] = Bt + (long)(nBase + ((r * 256 + tid) >> 2)) * ldb + ((tid * 8) & 31);
    }
    const int ldsOff = wave * 512;

    const int nT = kmax >> 6;          // K-step 64
    for (int kt = 0; kt < nT; ++kt) {
#pragma unroll
        for (int h = 0; h < 2; ++h)
#pragma unroll
            for (int r = 0; r < 2; ++r) {
                async_ld16(aP[r] + h * 32, &sA[h * 4096 + r * 2048 + ldsOff]);
                async_ld16(bP[r] + h * 32, &sB[h * 4096 + r * 2048 + ldsOff]);
            }
#pragma unroll
        for (int r = 0; r < 2; ++r) { aP[r] += 64; bP[r] += 64; }
        __syncthreads();

#pragma unroll
        for (int h = 0; h < 2; ++h) {
            f16x8 af[4], bf[4];
#pragma unroll
            for (int i = 0; i < 4; ++i)
                af[i] = *(const f16x8*)&sA[h * 4096 + (wrow * 64 + i * 16 + l16) * 32 + quad * 8];
#pragma unroll
            for (int j = 0; j < 4; ++j)
                bf[j] = *(const f16x8*)&sB[h * 4096 + (wcol * 64 + j * 16 + l16) * 32 + quad * 8];
#pragma unroll
            for (int i = 0; i < 4; ++i)
#pragma unroll
                for (int j = 0; j < 4; ++j)
                    acc[i][j] = __builtin_amdgcn_mfma_f32_16x16x32_f16(af[i], bf[j], acc[i][j], 0, 0, 0);
        }
        __syncthreads();
    }

    // ---- epilogues. C/D layout: col = lane&15, row = quad*4 + reg  [m89] ----
    if (MODE == 0) {
        const int seg = nBase >> 10;
        const float* bs = (seg == 0) ? b_q : (seg == 1) ? b_k : b_v;
        const int lcb = (nBase & 1023) + wcol * 64;
        float bvv[4];
#pragma unroll
        for (int j = 0; j < 4; ++j) bvv[j] = bs[lcb + j * 16 + l16];

        if (seg < 2) {
            // scalar stores but 64 consecutive f16 per wave-instr: fully
            // line-coalesced (r4's f16x4 row-scatter was SLOWER).
            f16* dst = (seg == 0) ? (f16*)C0 : (f16*)C1;
#pragma unroll
            for (int i = 0; i < 4; ++i)
#pragma unroll
                for (int j = 0; j < 4; ++j)
#pragma unroll
                    for (int r = 0; r < 4; ++r) {
                        const int row = mBase + wrow * 64 + i * 16 + quad * 4 + r;
                        dst[(long)row * 1024 + lcb + j * 16 + l16] = (f16)(acc[i][j][r] + bvv[j]);
                    }
        } else {
            // V: transpose tile through LDS, store coalesced along s.
            const int b = mBase >> 11, s0 = mBase & 2047;
            f16* epiT = smem;   // 64 x 136 f16
#pragma unroll
            for (int h = 0; h < 2; ++h) {
                if (wcol == h) {
#pragma unroll
                    for (int i = 0; i < 4; ++i)
#pragma unroll
                        for (int j = 0; j < 4; ++j) {
                            f16x4v pk;
#pragma unroll
                            for (int r = 0; r < 4; ++r)
                                pk[r] = (f16)(acc[i][j][r] + bvv[j]);
                            *(f16x4v*)&epiT[(j * 16 + l16) * 136 + wrow * 64 + i * 16 + quad * 4] = pk;
                        }
                }
                __syncthreads();
                const int er = tid >> 2;
                f16* dst = (f16*)C2 +
                    ((long)b * 1024 + (nBase & 1023) + h * 64 + er) * 2048 + s0;
#pragma unroll
                for (int cc = 0; cc < 4; ++cc) {
                    const int ch = (tid & 3) + cc * 4;
                    *(f16x8*)&dst[ch * 8] = *(const f16x8*)&epiT[er * 136 + ch * 8];
                }
                __syncthreads();
            }
        }
    } else if (MODE == 2) {
        f16* Crow = (f16*)C0 + (long)bz * strideCb;
        float* rsb = rowsum + bz * 2048;
#pragma unroll
        for (int i = 0; i < 4; ++i) {
            float rs[4] = {0.f, 0.f, 0.f, 0.f};
#pragma unroll
            for (int j = 0; j < 4; ++j)
#pragma unroll
                for (int r = 0; r < 4; ++r) {
                    const int row = mBase + wrow * 64 + i * 16 + quad * 4 + r;
                    const int col = nBase + wcol * 64 + j * 16 + l16;
                    float e = __expf(acc[i][j][r] * 0.03125f);
                    if (masked && col > row) e = 0.f;
                    const f16 hv = (f16)e;
                    Crow[(long)row * 2048 + col] = hv;
                    rs[r] += (float)hv;
                }
#pragma unroll
            for (int r = 0; r < 4; ++r) {
                float s = rs[r];
                s += __shfl_xor(s, 1);
                s += __shfl_xor(s, 2);
                s += __shfl_xor(s, 4);
                s += __shfl_xor(s, 8);
                if (l16 == 0) {
                    const int row = mBase + wrow * 64 + i * 16 + quad * 4 + r;
                    atomicAdd(&rsb[row], s);
                }
            }
        }
    } else {  // MODE 3
        float* Crow = (float*)C0 + (long)bz * strideCb;
        const float* rsb = rowsum + bz * 2048;
#pragma unroll
        for (int i = 0; i < 4; ++i)
#pragma unroll
            for (int r = 0; r < 4; ++r) {
                const int row = mBase + wrow * 64 + i * 16 + quad * 4 + r;
                const float inv = 1.f / rsb[row];
#pragma unroll
                for (int j = 0; j < 4; ++j) {
                    const int col = nBase + wcol * 64 + j * 16 + l16;
                    Crow[(long)row * 1024 + col] = acc[i][j][r] * inv;
                }
            }
    }
}

__global__ void cvt_inp(const float* __restrict__ in, f16* __restrict__ out, int n4)
{
    const int i = blockIdx.x * blockDim.x + threadIdx.x;
    if (i >= n4) return;
    const float4 v = ((const float4*)in)[i];
    f16x4v o;
    o[0] = (f16)v.x; o[1] = (f16)v.y; o[2] = (f16)v.z; o[3] = (f16)v.w;
    ((f16x4v*)out)[i] = o;
}

// three 1024x1024 weight matrices -> contiguous f16 [3072][1024]
__global__ void cvt_w3(const float* __restrict__ W0, const float* __restrict__ W1,
                       const float* __restrict__ W2, f16* __restrict__ out)
{
    const int bxx = blockIdx.x;            // 3072 blocks
    const int which = bxx >> 10;
    const float* src = (which == 0) ? W0 : (which == 1) ? W1 : W2;
    const int i = (bxx & 1023) * 256 + threadIdx.x;
    const float4 v = ((const float4*)src)[i];
    f16x4v o;
    o[0] = (f16)v.x; o[1] = (f16)v.y; o[2] = (f16)v.z; o[3] = (f16)v.w;
    ((f16x4v*)(out + (long)which * 1024 * 1024))[i] = o;
}

extern "C" void kernel_launch(void* const* d_in, const int* in_sizes, int n_in,
                              void* d_out, int out_size, void* d_ws, size_t ws_size,
                              hipStream_t stream)
{
    const float* inp = (const float*)d_in[0];
    const int* masked = (const int*)d_in[1];
    const float* Wq = (const float*)d_in[2];
    const float* bq = (const float*)d_in[3];
    const float* Wk = (const float*)d_in[4];
    const float* bk = (const float*)d_in[5];
    const float* Wv = (const float*)d_in[6];
    const float* bv = (const float*)d_in[7];
    float* out = (float*)d_out;

    const int Bb = 4, S = 2048, E = 1024;
    const long nTok = (long)Bb * S;   // 8192

    // workspace (~102 MB). W3 segments must stay contiguous (one Bt operand).
    char* ws = (char*)d_ws;
    f16* inp16 = (f16*)ws;   ws += nTok * E * 2;         // 16 MB
    f16* W3    = (f16*)ws;   ws += (long)3 * E * E * 2;  //  6 MB
    f16* Q16   = (f16*)ws;   ws += nTok * E * 2;         // 16 MB
    f16* K16   = (f16*)ws;   ws += nTok * E * 2;         // 16 MB
    f16* Vt16  = (f16*)ws;   ws += nTok * E * 2;         // 16 MB ([b][e][s])
    f16* P16   = (f16*)ws;   ws += (long)Bb * S * S * 2; // 32 MB
    float* rsum = (float*)ws; ws += nTok * 4;            // 32 KB

    dim3 blk(256);

    hipMemsetAsync(rsum, 0, nTok * 4, stream);
    cvt_inp<<<(int)(nTok * E / 4 / 256), blk, 0, stream>>>(inp, inp16, (int)(nTok * E / 4));
    cvt_w3<<<3 * 1024, blk, 0, stream>>>(Wq, Wk, Wv, W3);

    // fused QKV: A = inp (8192x1024 tokens), Bt = W3 (3072x1024)
    gemm_bt<0><<<dim3(3 * E / 128, (int)(nTok / 128), 1), blk, 0, stream>>>(
        inp16, 0, E, W3, 0, E, bq, bk, bv, nullptr,
        Q16, K16, Vt16, 0, E, nullptr);

    // P = exp(QK^T/32) + rowsum atomics (128x128 tiles, causal skip,
    // heavy rows first)
    gemm_bt<2><<<dim3(S / 128, S / 128, Bb), blk, 0, stream>>>(
        Q16, (long)S * E, E, K16, (long)S * E, E, nullptr, nullptr, nullptr, rsum,
        P16, nullptr, nullptr, (long)S * S, E, masked);

    // out = (P @ V)/rowsum (128x128 tiles, K causal-limited, heavy first)
    gemm_bt<3><<<dim3(E / 128, S / 128, Bb), blk, 0, stream>>>(
        P16, (long)S * S, S, Vt16, (long)E * S, S, nullptr, nullptr, nullptr, rsum,
        out, nullptr, nullptr, (long)S * E, S, masked);
}

// Round 8
// 265.488 us; speedup vs baseline: 1.5146x; 1.0450x over previous
//
#include <hip/hip_runtime.h>

typedef _Float16 f16;
typedef f16 f16x8 __attribute__((ext_vector_type(8)));
typedef f16 f16x4v __attribute__((ext_vector_type(4)));
typedef float f32x4 __attribute__((ext_vector_type(4)));

// async global->LDS, 16B per lane. LDS dest is wave-uniform base; HW scatters
// lane i's 16B to base + i*16. (No padding possible -> keep BK=32 layout.)
// NOTE (r6): direct per-fragment global loads instead of LDS staging regress
// 4x (MfmaUtil 4.5%) -- exposed VMEM latency. Keep LDS staging.
__device__ __forceinline__ void async_ld16(const void* g, void* l) {
    __builtin_amdgcn_global_load_lds(
        (const __attribute__((address_space(1))) unsigned int*)g,
        (__attribute__((address_space(3))) unsigned int*)l, 16, 0, 0);
}

// C[m,n] = sum_k A[m,k] * Bt[n,k], tile 128 x 128, K-step 64 = 2 x BK32.
// MODE 0: 256 thr (4 waves, 64x64/wave). fused QKV, N=3072; seg(nBase>>10):
//       0 -> Q16 (+b_q), 1 -> K16 (+b_k), 2 -> Vt16 [b][e][s] via LDS transp.
// MODE 2: 512 thr (8 waves, 32x64/wave -- r7 lesson: scores/PV are wave-
//       starved at 2.1 blocks/CU; 8-wave blocks double resident waves/CU).
//       P[q][k] = exp(score/32) f16, causal-zeroed; rowsum atomics.
// MODE 3: 512 thr. out = (P @ V) / rowsum[q], fp32; K-loop causal-limited.
template <int MODE>
__global__ __launch_bounds__((MODE == 0) ? 256 : 512) void gemm_bt(
    const f16* __restrict__ A, long strideAb, int lda,
    const f16* __restrict__ Bt, long strideBb, int ldb,
    const float* __restrict__ b_q, const float* __restrict__ b_k,
    const float* __restrict__ b_v, float* __restrict__ rowsum,
    void* __restrict__ C0, void* __restrict__ C1, void* __restrict__ C2,
    long strideCb, int K,
    const int* __restrict__ maskedp)
{
    constexpr int NT  = (MODE == 0) ? 256 : 512;   // threads
    constexpr int NI  = (MODE == 0) ? 4 : 2;       // 16-row blocks per wave
    constexpr int RND = (128 * 32) / (NT * 8);     // staging rounds per subtile

    const int bx = blockIdx.x, bz = blockIdx.z;
    // heavy (long-K / unskipped) rows launch first for causal modes
    const int by = (MODE >= 2) ? (gridDim.y - 1 - blockIdx.y) : blockIdx.y;
    const int masked = maskedp ? *maskedp : 1;
    if (MODE == 2 && masked && bx > by) return;      // fully-masked tile
    int kmax = K;
    if (MODE == 3 && masked) kmax = min(K, (by + 1) * 128);

    A  += (long)bz * strideAb;
    Bt += (long)bz * strideBb;

    // two BK=32 sub-tiles of A (128x32) + two of B (128x32)
    __shared__ __align__(16) f16 smem[256 * 64];
    f16* sA = smem;                    // halves at h*4096
    f16* sB = smem + 128 * 64;

    const int tid  = threadIdx.x;
    const int wave = tid >> 6, lane = tid & 63;
    const int wrow = wave >> 1, wcol = wave & 1;
    const int quad = lane >> 4, l16 = lane & 15;
    const int mBase = by * 128, nBase = bx * 128;

    f32x4 acc[NI][4];
#pragma unroll
    for (int i = 0; i < NI; ++i)
#pragma unroll
        for (int j = 0; j < 4; ++j)
            acc[i][j] = (f32x4){0.f, 0.f, 0.f, 0.f};

    // pointer-bumped staging addresses (+64 f16 per outer iter)
    const f16* aP[RND];
    const f16* bP[RND];
#pragma unroll
    for (int r = 0; r < RND; ++r) {
        aP[r] = A  + (long)(mBase + ((r * NT + tid) >> 2)) * lda + ((tid * 8) & 31);
        bP[r] = Bt + (long)(nBase + ((r * NT + tid) >> 2)) * ldb + ((tid * 8) & 31);
    }
    const int ldsOff = wave * 512;

    const int nT = kmax >> 6;          // K-step 64
    for (int kt = 0; kt < nT; ++kt) {
#pragma unroll
        for (int h = 0; h < 2; ++h)
#pragma unroll
            for (int r = 0; r < RND; ++r) {
                async_ld16(aP[r] + h * 32, &sA[h * 4096 + r * (NT * 8) + ldsOff]);
                async_ld16(bP[r] + h * 32, &sB[h * 4096 + r * (NT * 8) + ldsOff]);
            }
#pragma unroll
        for (int r = 0; r < RND; ++r) { aP[r] += 64; bP[r] += 64; }
        __syncthreads();

#pragma unroll
        for (int h = 0; h < 2; ++h) {
            f16x8 af[NI], bf[4];
#pragma unroll
            for (int i = 0; i < NI; ++i)
                af[i] = *(const f16x8*)&sA[h * 4096 + (wrow * (16 * NI) + i * 16 + l16) * 32 + quad * 8];
#pragma unroll
            for (int j = 0; j < 4; ++j)
                bf[j] = *(const f16x8*)&sB[h * 4096 + (wcol * 64 + j * 16 + l16) * 32 + quad * 8];
#pragma unroll
            for (int i = 0; i < NI; ++i)
#pragma unroll
                for (int j = 0; j < 4; ++j)
                    acc[i][j] = __builtin_amdgcn_mfma_f32_16x16x32_f16(af[i], bf[j], acc[i][j], 0, 0, 0);
        }
        __syncthreads();
    }

    // ---- epilogues. C/D layout: col = lane&15, row = quad*4 + reg  [m89] ----
    if (MODE == 0) {
        const int seg = nBase >> 10;
        const float* bs = (seg == 0) ? b_q : (seg == 1) ? b_k : b_v;
        const int lcb = (nBase & 1023) + wcol * 64;
        float bvv[4];
#pragma unroll
        for (int j = 0; j < 4; ++j) bvv[j] = bs[lcb + j * 16 + l16];

        if (seg < 2) {
            // scalar stores but 64 consecutive f16 per wave-instr: fully
            // line-coalesced (r4's f16x4 row-scatter was SLOWER).
            f16* dst = (seg == 0) ? (f16*)C0 : (f16*)C1;
#pragma unroll
            for (int i = 0; i < 4; ++i)
#pragma unroll
                for (int j = 0; j < 4; ++j)
#pragma unroll
                    for (int r = 0; r < 4; ++r) {
                        const int row = mBase + wrow * 64 + i * 16 + quad * 4 + r;
                        dst[(long)row * 1024 + lcb + j * 16 + l16] = (f16)(acc[i][j][r] + bvv[j]);
                    }
        } else {
            // V: transpose tile through LDS, store coalesced along s.
            const int b = mBase >> 11, s0 = mBase & 2047;
            f16* epiT = smem;   // 64 x 136 f16
#pragma unroll
            for (int h = 0; h < 2; ++h) {
                if (wcol == h) {
#pragma unroll
                    for (int i = 0; i < 4; ++i)
#pragma unroll
                        for (int j = 0; j < 4; ++j) {
                            f16x4v pk;
#pragma unroll
                            for (int r = 0; r < 4; ++r)
                                pk[r] = (f16)(acc[i][j][r] + bvv[j]);
                            *(f16x4v*)&epiT[(j * 16 + l16) * 136 + wrow * 64 + i * 16 + quad * 4] = pk;
                        }
                }
                __syncthreads();
                const int er = tid >> 2;
                f16* dst = (f16*)C2 +
                    ((long)b * 1024 + (nBase & 1023) + h * 64 + er) * 2048 + s0;
#pragma unroll
                for (int cc = 0; cc < 4; ++cc) {
                    const int ch = (tid & 3) + cc * 4;
                    *(f16x8*)&dst[ch * 8] = *(const f16x8*)&epiT[er * 136 + ch * 8];
                }
                __syncthreads();
            }
        }
    } else if (MODE == 2) {
        f16* Crow = (f16*)C0 + (long)bz * strideCb;
        float* rsb = rowsum + bz * 2048;
#pragma unroll
        for (int i = 0; i < NI; ++i) {
            float rs[4] = {0.f, 0.f, 0.f, 0.f};
#pragma unroll
            for (int j = 0; j < 4; ++j)
#pragma unroll
                for (int r = 0; r < 4; ++r) {
                    const int row = mBase + wrow * 32 + i * 16 + quad * 4 + r;
                    const int col = nBase + wcol * 64 + j * 16 + l16;
                    float e = __expf(acc[i][j][r] * 0.03125f);
                    if (masked && col > row) e = 0.f;
                    const f16 hv = (f16)e;
                    Crow[(long)row * 2048 + col] = hv;
                    rs[r] += (float)hv;
                }
#pragma unroll
            for (int r = 0; r < 4; ++r) {
                float s = rs[r];
                s += __shfl_xor(s, 1);
                s += __shfl_xor(s, 2);
                s += __shfl_xor(s, 4);
                s += __shfl_xor(s, 8);
                if (l16 == 0) {
                    const int row = mBase + wrow * 32 + i * 16 + quad * 4 + r;
                    atomicAdd(&rsb[row], s);
                }
            }
        }
    } else {  // MODE 3
        float* Crow = (float*)C0 + (long)bz * strideCb;
        const float* rsb = rowsum + bz * 2048;
#pragma unroll
        for (int i = 0; i < NI; ++i)
#pragma unroll
            for (int r = 0; r < 4; ++r) {
                const int row = mBase + wrow * 32 + i * 16 + quad * 4 + r;
                const float inv = 1.f / rsb[row];
#pragma unroll
                for (int j = 0; j < 4; ++j) {
                    const int col = nBase + wcol * 64 + j * 16 + l16;
                    Crow[(long)row * 1024 + col] = acc[i][j][r] * inv;
                }
            }
    }
}

__global__ void cvt_inp(const float* __restrict__ in, f16* __restrict__ out, int n4)
{
    const int i = blockIdx.x * blockDim.x + threadIdx.x;
    if (i >= n4) return;
    const float4 v = ((const float4*)in)[i];
    f16x4v o;
    o[0] = (f16)v.x; o[1] = (f16)v.y; o[2] = (f16)v.z; o[3] = (f16)v.w;
    ((f16x4v*)out)[i] = o;
}

// three 1024x1024 weight matrices -> contiguous f16 [3072][1024]
__global__ void cvt_w3(const float* __restrict__ W0, const float* __restrict__ W1,
                       const float* __restrict__ W2, f16* __restrict__ out)
{
    const int bxx = blockIdx.x;            // 3072 blocks
    const int which = bxx >> 10;
    const float* src = (which == 0) ? W0 : (which == 1) ? W1 : W2;
    const int i = (bxx & 1023) * 256 + threadIdx.x;
    const float4 v = ((const float4*)src)[i];
    f16x4v o;
    o[0] = (f16)v.x; o[1] = (f16)v.y; o[2] = (f16)v.z; o[3] = (f16)v.w;
    ((f16x4v*)(out + (long)which * 1024 * 1024))[i] = o;
}

extern "C" void kernel_launch(void* const* d_in, const int* in_sizes, int n_in,
                              void* d_out, int out_size, void* d_ws, size_t ws_size,
                              hipStream_t stream)
{
    const float* inp = (const float*)d_in[0];
    const int* masked = (const int*)d_in[1];
    const float* Wq = (const float*)d_in[2];
    const float* bq = (const float*)d_in[3];
    const float* Wk = (const float*)d_in[4];
    const float* bk = (const float*)d_in[5];
    const float* Wv = (const float*)d_in[6];
    const float* bv = (const float*)d_in[7];
    float* out = (float*)d_out;

    const int Bb = 4, S = 2048, E = 1024;
    const long nTok = (long)Bb * S;   // 8192

    // workspace (~102 MB). W3 segments must stay contiguous (one Bt operand).
    char* ws = (char*)d_ws;
    f16* inp16 = (f16*)ws;   ws += nTok * E * 2;         // 16 MB
    f16* W3    = (f16*)ws;   ws += (long)3 * E * E * 2;  //  6 MB
    f16* Q16   = (f16*)ws;   ws += nTok * E * 2;         // 16 MB
    f16* K16   = (f16*)ws;   ws += nTok * E * 2;         // 16 MB
    f16* Vt16  = (f16*)ws;   ws += nTok * E * 2;         // 16 MB ([b][e][s])
    f16* P16   = (f16*)ws;   ws += (long)Bb * S * S * 2; // 32 MB
    float* rsum = (float*)ws; ws += nTok * 4;            // 32 KB

    dim3 blk(256);

    hipMemsetAsync(rsum, 0, nTok * 4, stream);
    cvt_inp<<<(int)(nTok * E / 4 / 256), blk, 0, stream>>>(inp, inp16, (int)(nTok * E / 4));
    cvt_w3<<<3 * 1024, blk, 0, stream>>>(Wq, Wk, Wv, W3);

    // fused QKV: A = inp (8192x1024 tokens), Bt = W3 (3072x1024)
    gemm_bt<0><<<dim3(3 * E / 128, (int)(nTok / 128), 1), blk, 0, stream>>>(
        inp16, 0, E, W3, 0, E, bq, bk, bv, nullptr,
        Q16, K16, Vt16, 0, E, nullptr);

    // P = exp(QK^T/32) + rowsum atomics (128x128 tiles, 8-wave blocks,
    // causal skip, heavy rows first)
    gemm_bt<2><<<dim3(S / 128, S / 128, Bb), dim3(512), 0, stream>>>(
        Q16, (long)S * E, E, K16, (long)S * E, E, nullptr, nullptr, nullptr, rsum,
        P16, nullptr, nullptr, (long)S * S, E, masked);

    // out = (P @ V)/rowsum (128x128 tiles, 8-wave blocks, K causal-limited)
    gemm_bt<3><<<dim3(E / 128, S / 128, Bb), dim3(512), 0, stream>>>(
        P16, (long)S * S, S, Vt16, (long)E * S, S, nullptr, nullptr, nullptr, rsum,
        out, nullptr, nullptr, (long)S * E, S, masked);
}